// Round 9
// baseline (753.843 us; speedup 1.0000x reference)
//
#include <hip/hip_runtime.h>

typedef unsigned int uint;
typedef unsigned short ushort;
typedef __attribute__((ext_vector_type(8))) short bf16x8;   // MFMA A/B frag (8 bf16)
typedef __attribute__((ext_vector_type(4))) float f32x4;    // MFMA C/D frag

// Problem constants
#define C_IN   48
#define C3     144
#define HW     56
#define SSP    3136
#define DW     49
#define DPAD   64            // padded head dim; yf cols 49..63 zero, yfT row 56 ones
#define NROWS  9216

// Attention config: block = 4 waves sharing LDS-staged K/V tiles, 128 queries.
#define NSPLIT 8             // key splits
#define TPS    18            // tiles per split = 144/NSPLIT
#define NBLK   576           // grid = 72 query-blocks x 8 splits; 3 blk/CU x 256 CU = 768 slots >= 576

#define CSC 0.02944245f      // 1/(49*ln2): exp2(qk*CSC)=exp(qk/49)

// ws layout (bytes):
//   yf    bf16 [9216][64]   : 0        .. 1179648
//   yfT   bf16 [64][9216]   : 1179648  .. 2359296
//   opart bf16 [8][49][9216]: 2359296  .. 9584640
//   esum  f32  [8][9216]    : 9584640  .. 9879552
//   barrier counters (2 uint): 9879552 .. 9879808 (zeroed via hipMemsetAsync)
#define YF_B    0
#define YFT_B   1179648
#define OPART_B 2359296
#define ESUM_B  (OPART_B + NSPLIT * DW * NROWS * 2)
#define BAR_B   (ESUM_B + NSPLIT * NROWS * 4)

__device__ __forceinline__ ushort f32_to_bf16_rne(float x) {
  uint b = __float_as_uint(x);
  b += 0x7fffu + ((b >> 16) & 1u);
  return (ushort)(b >> 16);
}
__device__ __forceinline__ float bf16_to_f32(ushort u) {
  return __uint_as_float(((uint)u) << 16);
}
__device__ __forceinline__ void async_copy16(const void* g, void* l) {
  __builtin_amdgcn_global_load_lds(
      (const __attribute__((address_space(1))) unsigned int*)g,
      (__attribute__((address_space(3))) unsigned int*)l, 16, 0, 0);
}

// Device-scope grid barrier. Safe because all NBLK blocks are co-resident:
// LDS 51200 B -> 3 blocks/CU (153.6/160 KiB), VGPR capped by launch_bounds,
// 768 slots >= 576, and spinning blocks never free their slots. __syncthreads
// drains vmcnt so all block stores are at L2; lane-0's __threadfence then
// writes back the XCD's L2 (device visibility) / invalidates on the way out.
__device__ __forceinline__ void grid_barrier(uint* cnt) {
  __syncthreads();
  if (threadIdx.x == 0) {
    __threadfence();   // release: L2 writeback -> visible across XCDs
    __hip_atomic_fetch_add(cnt, 1u, __ATOMIC_RELEASE, __HIP_MEMORY_SCOPE_AGENT);
    while (__hip_atomic_load(cnt, __ATOMIC_ACQUIRE, __HIP_MEMORY_SCOPE_AGENT) < NBLK) {
      __builtin_amdgcn_s_sleep(2);
    }
    __threadfence();   // acquire: invalidate L1/L2 so reads see fresh data
  }
  __syncthreads();
}

// ---------------------------------------------------------------------------
// ONE kernel, 576 blocks x 256 threads, 3 phases split by manual grid barrier
// (no dispatch boundaries):
//   P1 conv (grid-stride, 4 items/thread) -> yf row-major + yfT scatter
//   P2 MFMA flash attention (global_load_lds double-buffered K/V)
//   P3 merge + pointwise + bias + residual (blocks < 448)
// ---------------------------------------------------------------------------
__global__ __launch_bounds__(256, 3) void mega_kernel(
    const float* __restrict__ x, const float* __restrict__ w3,
    const float* __restrict__ w5, const float* __restrict__ w7,
    const float* __restrict__ pwm, const float* __restrict__ pb,
    ushort* __restrict__ yf, ushort* __restrict__ yfT,
    ushort* __restrict__ opart, float* __restrict__ esum_g,
    uint* __restrict__ bar, float* __restrict__ out) {
  // [Kbuf0 8K][Kbuf1 8K][Vbuf0 8K][Vbuf1 8K][P 4x32x72 ushort 18K] = 51200 B
  __shared__ __align__(16) char smem[51200];
  const int tid = threadIdx.x;

  // ================= Phase 1: depthwise convs, dual-layout store ===========
  for (int idx = blockIdx.x * 256 + tid; idx < NROWS * DPAD; idx += NBLK * 256) {
    int r = idx >> 6, t = idx & 63;
    if (t >= DW) {
      yf[idx] = 0;                               // K/Q pad cols must be zero
      if (t == 56) yfT[56 * NROWS + r] = 0x3F80; // ones row -> denominator
      continue;
    }
    int g = r / C3, c3 = r - g * C3;
    int flat = g * DW + t;
    int h = flat / HW, w = flat - h * HW;
    int grp = c3 / C_IN, c = c3 - grp * C_IN;
    const float* wk; int ks;
    if (grp == 0)      { wk = w3 + c * 9;  ks = 3; }
    else if (grp == 1) { wk = w5 + c * 25; ks = 5; }
    else               { wk = w7 + c * 49; ks = 7; }
    int p = ks >> 1;
    const float* xc = x + c * SSP;
    float val = 0.f;
    for (int dy = 0; dy < ks; dy++) {
      int hy = h + dy - p;
      if (hy < 0 || hy >= HW) continue;
      const float* xr = xc + hy * HW;
      const float* wr = wk + dy * ks;
      for (int dx = 0; dx < ks; dx++) {
        int wx = w + dx - p;
        if (wx < 0 || wx >= HW) continue;
        val += xr[wx] * wr[dx];
      }
    }
    ushort ov = f32_to_bf16_rne(val);
    yf[idx] = ov;
    yfT[t * NROWS + r] = ov;
  }

  grid_barrier(bar + 0);

  // ================= Phase 2: MFMA flash attention =========================
  {
    const int bid = blockIdx.x;
    const int qb = bid % 72, sp = bid / 72;
    const int w = tid >> 6, lane = tid & 63;
    const int q = lane >> 4, c = lane & 15;
    const int m0 = qb * 128 + w * 32;   // this wave's 32 queries
    ushort* Pm = (ushort*)(smem + 32768) + w * (32 * 72);

    // Q B-frags (pre-scaled by CSC): 16B loads straight from yf.
    bf16x8 qf[2][2];
#pragma unroll
    for (int mt = 0; mt < 2; mt++)
#pragma unroll
      for (int ds = 0; ds < 2; ds++) {
        bf16x8 raw = *(const bf16x8*)&yf[(m0 + mt * 16 + c) * 64 + ds * 32 + q * 8];
        short tmp[8];
#pragma unroll
        for (int j = 0; j < 8; j++)
          tmp[j] = (short)f32_to_bf16_rne(bf16_to_f32((ushort)raw[j]) * CSC);
        qf[mt][ds] = *(bf16x8*)tmp;
      }

    f32x4 o[4][2];
#pragma unroll
    for (int dt = 0; dt < 4; dt++)
#pragma unroll
      for (int mt = 0; mt < 2; mt++) o[dt][mt] = (f32x4)0.f;

    const int s0 = w, s1 = w + 4;   // this wave's DMA slab pair

    // ---- stage tile 0 into buffer 0 ----
    {
      const int k0 = (sp * TPS) * 64;
      char* Kb = smem;
      char* Vb = smem + 16384;
      async_copy16(yf + (k0 + lane) * 64 + s0 * 8, Kb + s0 * 1024);
      async_copy16(yf + (k0 + lane) * 64 + s1 * 8, Kb + s1 * 1024);
      async_copy16(yfT + lane * NROWS + k0 + s0 * 8, Vb + s0 * 1024);
      async_copy16(yfT + lane * NROWS + k0 + s1 * 8, Vb + s1 * 1024);
    }
    __syncthreads();

    for (int it = 0; it < TPS; it++) {
      const int cur = it & 1;
      if (it + 1 < TPS) {
        const int k1 = (sp * TPS + it + 1) * 64;
        char* Kb = smem + (cur ^ 1) * 8192;
        char* Vb = smem + 16384 + (cur ^ 1) * 8192;
        async_copy16(yf + (k1 + lane) * 64 + s0 * 8, Kb + s0 * 1024);
        async_copy16(yf + (k1 + lane) * 64 + s1 * 8, Kb + s1 * 1024);
        async_copy16(yfT + lane * NROWS + k1 + s0 * 8, Vb + s0 * 1024);
        async_copy16(yfT + lane * NROWS + k1 + s1 * 8, Vb + s1 * 1024);
      }

      const char* Kb = smem + cur * 8192;
      const char* Vb = smem + 16384 + cur * 8192;

      // ---- S^T = K . Q^T ----
      f32x4 s[4][2];
#pragma unroll
      for (int nt = 0; nt < 4; nt++) {
        bf16x8 a0 = *(const bf16x8*)(Kb + q * 1024 + (nt * 16 + c) * 16);
        bf16x8 a1 = *(const bf16x8*)(Kb + (4 + q) * 1024 + (nt * 16 + c) * 16);
        s[nt][0] = (f32x4)0.f; s[nt][1] = (f32x4)0.f;
        s[nt][0] = __builtin_amdgcn_mfma_f32_16x16x32_bf16(a0, qf[0][0], s[nt][0], 0, 0, 0);
        s[nt][1] = __builtin_amdgcn_mfma_f32_16x16x32_bf16(a0, qf[1][0], s[nt][1], 0, 0, 0);
        s[nt][0] = __builtin_amdgcn_mfma_f32_16x16x32_bf16(a1, qf[0][1], s[nt][0], 0, 0, 0);
        s[nt][1] = __builtin_amdgcn_mfma_f32_16x16x32_bf16(a1, qf[1][1], s[nt][1], 0, 0, 0);
      }

      // ---- p = exp2(s); pack bf16 P into wave-private LDS ----
#pragma unroll
      for (int nt = 0; nt < 4; nt++)
#pragma unroll
        for (int mt = 0; mt < 2; mt++) {
          f32x4 sv = s[nt][mt];
          float p0 = __builtin_amdgcn_exp2f(sv[0]);
          float p1 = __builtin_amdgcn_exp2f(sv[1]);
          float p2 = __builtin_amdgcn_exp2f(sv[2]);
          float p3 = __builtin_amdgcn_exp2f(sv[3]);
          uint d0 = (__float_as_uint(p0) >> 16) | (__float_as_uint(p1) & 0xffff0000u);
          uint d1 = (__float_as_uint(p2) >> 16) | (__float_as_uint(p3) & 0xffff0000u);
          *(uint2*)&Pm[(mt * 16 + c) * 72 + nt * 16 + q * 4] = make_uint2(d0, d1);
        }

      // ---- O^T += V^T . P^T ----
      bf16x8 bp[2][2];
#pragma unroll
      for (int mt = 0; mt < 2; mt++)
#pragma unroll
        for (int nc = 0; nc < 2; nc++)
          bp[mt][nc] = *(const bf16x8*)&Pm[(mt * 16 + c) * 72 + nc * 32 + q * 8];
#pragma unroll
      for (int dt = 0; dt < 4; dt++) {
        bf16x8 v0 = *(const bf16x8*)(Vb + q * 1024 + (dt * 16 + c) * 16);
        bf16x8 v1 = *(const bf16x8*)(Vb + (4 + q) * 1024 + (dt * 16 + c) * 16);
        o[dt][0] = __builtin_amdgcn_mfma_f32_16x16x32_bf16(v0, bp[0][0], o[dt][0], 0, 0, 0);
        o[dt][1] = __builtin_amdgcn_mfma_f32_16x16x32_bf16(v0, bp[1][0], o[dt][1], 0, 0, 0);
        o[dt][0] = __builtin_amdgcn_mfma_f32_16x16x32_bf16(v1, bp[0][1], o[dt][0], 0, 0, 0);
        o[dt][1] = __builtin_amdgcn_mfma_f32_16x16x32_bf16(v1, bp[1][1], o[dt][1], 0, 0, 0);
      }

      if (it + 1 < TPS) __syncthreads();
    }

    // ---- epilogue: each wave writes its own 32 queries' partials ----
#pragma unroll
    for (int dt = 0; dt < 4; dt++)
#pragma unroll
      for (int mt = 0; mt < 2; mt++)
#pragma unroll
        for (int r = 0; r < 4; r++) {
          int d = dt * 16 + q * 4 + r;
          int m = m0 + mt * 16 + c;
          float v = o[dt][mt][r];
          if (d < DW) {
            opart[(sp * DW + d) * NROWS + m] = f32_to_bf16_rne(v);
          } else if (d == 56) {
            esum_g[sp * NROWS + m] = v;   // softmax denominator (exact f32)
          }
        }
  }

  grid_barrier(bar + 16);   // second counter (separate cache line)

  // ================= Phase 3: merge + pointwise + bias + residual ==========
  if (blockIdx.x < 448) {
    float* vb = (float*)smem;                    // [7*145]
    float* inv_es = (float*)smem + 7 * 145;      // [144]
    const int g = blockIdx.x / 7, tch = blockIdx.x % 7;
    const int t0 = tch * 7;

    if (tid < 144) {
      int r = g * C3 + tid;
      float e = 0.f;
#pragma unroll
      for (int sp = 0; sp < NSPLIT; sp++) e += esum_g[sp * NROWS + r];
      inv_es[tid] = 1.f / e;
    }
    __syncthreads();

    for (int j = tid; j < 7 * 144; j += 256) {
      int tt = j / 144, i = j - tt * 144;
      int r = g * C3 + i, t = t0 + tt;
      float ov = 0.f;
#pragma unroll
      for (int sp = 0; sp < NSPLIT; sp++)
        ov += bf16_to_f32(opart[(sp * DW + t) * NROWS + r]);
      vb[tt * 145 + i] = ov * inv_es[i];
    }
    __syncthreads();

    for (int j = tid; j < C_IN * 7; j += 256) {
      int o = j / 7, tt = j - o * 7;
      int t = t0 + tt;
      const float* pwo = pwm + o * C3;
      const float* vrow = &vb[tt * 145];
      float a0 = 0.f, a1 = 0.f, a2 = 0.f, a3 = 0.f;
#pragma unroll
      for (int i = 0; i < C3; i += 4) {
        float4 wv = *(const float4*)&pwo[i];
        a0 += wv.x * vrow[i];
        a1 += wv.y * vrow[i + 1];
        a2 += wv.z * vrow[i + 2];
        a3 += wv.w * vrow[i + 3];
      }
      float acc = (a0 + a1) + (a2 + a3);
      int nh = g >> 3, nw = g & 7;
      int th = t / 7, tw = t - th * 7;
      int oidx = o * SSP + (nh * 7 + th) * HW + (nw * 7 + tw);
      out[oidx] = x[oidx] + pb[o] + acc;
    }
  }
}

// ---------------------------------------------------------------------------
extern "C" void kernel_launch(void* const* d_in, const int* in_sizes, int n_in,
                              void* d_out, int out_size, void* d_ws, size_t ws_size,
                              hipStream_t stream) {
  const float* x  = (const float*)d_in[0];
  const float* w3 = (const float*)d_in[1];
  const float* w5 = (const float*)d_in[2];
  const float* w7 = (const float*)d_in[3];
  const float* pw = (const float*)d_in[4];
  const float* pb = (const float*)d_in[5];
  float* out = (float*)d_out;
  char* ws = (char*)d_ws;

  ushort* yf    = (ushort*)(ws + YF_B);
  ushort* yfT   = (ushort*)(ws + YFT_B);
  ushort* opart = (ushort*)(ws + OPART_B);
  float*  esum  = (float*)(ws + ESUM_B);
  uint*   bar   = (uint*)(ws + BAR_B);

  // zero the barrier counters (d_ws is poisoned 0xAA before every launch)
  hipMemsetAsync(bar, 0, 256, stream);
  mega_kernel<<<NBLK, 256, 0, stream>>>(x, w3, w5, w7, pw, pb, yf, yfT, opart,
                                        esum, bar, out);
}

// Round 10
// 262.634 us; speedup vs baseline: 2.8703x; 2.8703x over previous
//
#include <hip/hip_runtime.h>

typedef unsigned int uint;
typedef unsigned short ushort;
typedef __attribute__((ext_vector_type(8))) short bf16x8;   // MFMA A/B frag (8 bf16)
typedef __attribute__((ext_vector_type(4))) float f32x4;    // MFMA C/D frag

// Problem constants
#define C_IN   48
#define C3     144
#define HW     56
#define SSP    3136
#define DW     49
#define DPAD   64            // padded head dim; yf cols 49..63 zero, yfT row 56 ones
#define NROWS  9216

// Attention config: block = 4 waves sharing LDS-staged K/V tiles, 128 queries.
#define NSPLIT 8             // key splits
#define TPS    18            // tiles per split = 144/NSPLIT
#define NBLK   576           // grid; 3 blk/CU x 256 CU = 768 slots >= 576 (co-residency proven in R9)

#define CSC 0.02944245f      // 1/(49*ln2): exp2(qk*CSC)=exp(qk/49)

// ws layout (bytes):
//   yf    bf16 [9216][64]   : 0        .. 1179648
//   yfT   bf16 [64][9216]   : 1179648  .. 2359296
//   opart bf16 [8][49][9216]: 2359296  .. 9584640
//   esum  f32  [8][9216]    : 9584640  .. 9879552
//   barrier counters        : 9879552  .. 9879808 (zeroed via hipMemsetAsync)
#define YF_B    0
#define YFT_B   1179648
#define OPART_B 2359296
#define ESUM_B  (OPART_B + NSPLIT * DW * NROWS * 2)
#define BAR_B   (ESUM_B + NSPLIT * NROWS * 4)

__device__ __forceinline__ ushort f32_to_bf16_rne(float x) {
  uint b = __float_as_uint(x);
  b += 0x7fffu + ((b >> 16) & 1u);
  return (ushort)(b >> 16);
}
__device__ __forceinline__ float bf16_to_f32(ushort u) {
  return __uint_as_float(((uint)u) << 16);
}
__device__ __forceinline__ void async_copy16(const void* g, void* l) {
  __builtin_amdgcn_global_load_lds(
      (const __attribute__((address_space(1))) unsigned int*)g,
      (__attribute__((address_space(3))) unsigned int*)l, 16, 0, 0);
}

// Device-scope grid barrier, cache-safe idiom:
//  - RELEASE fence once (L2 writeback -> coherent point), then RELAXED add.
//  - Spin on RELAXED agent-scope load: reads the coherent copy of THIS line
//    only — does NOT invalidate caches (R9's ACQUIRE-poll invalidated L1/L2
//    chip-wide every ~128cyc -> 719us at 59GB/s HBM-latency-bound).
//  - After release from spin: ONE ACQUIRE fence (invalidate) per block.
// Co-residency of all 576 blocks proven by R9 completing.
__device__ __forceinline__ void grid_barrier(uint* cnt) {
  __syncthreads();
  if (threadIdx.x == 0) {
    __builtin_amdgcn_fence(__ATOMIC_RELEASE, "agent");
    __hip_atomic_fetch_add(cnt, 1u, __ATOMIC_RELAXED, __HIP_MEMORY_SCOPE_AGENT);
    while (__hip_atomic_load(cnt, __ATOMIC_RELAXED, __HIP_MEMORY_SCOPE_AGENT) < NBLK) {
      __builtin_amdgcn_s_sleep(8);
    }
    __builtin_amdgcn_fence(__ATOMIC_ACQUIRE, "agent");
  }
  __syncthreads();
}

// ---------------------------------------------------------------------------
// ONE kernel, 576 blocks x 256 threads, 3 phases split by manual grid barrier
// (no dispatch boundaries):
//   P1 conv (grid-stride, 4 items/thread) -> yf row-major + yfT scatter
//   P2 MFMA flash attention (global_load_lds double-buffered K/V)
//   P3 merge + pointwise + bias + residual (blocks < 448)
// ---------------------------------------------------------------------------
__global__ __launch_bounds__(256, 3) void mega_kernel(
    const float* __restrict__ x, const float* __restrict__ w3,
    const float* __restrict__ w5, const float* __restrict__ w7,
    const float* __restrict__ pwm, const float* __restrict__ pb,
    ushort* __restrict__ yf, ushort* __restrict__ yfT,
    ushort* __restrict__ opart, float* __restrict__ esum_g,
    uint* __restrict__ bar, float* __restrict__ out) {
  // [Kbuf0 8K][Kbuf1 8K][Vbuf0 8K][Vbuf1 8K][P 4x32x72 ushort 18K] = 51200 B
  __shared__ __align__(16) char smem[51200];
  const int tid = threadIdx.x;

  // ================= Phase 1: depthwise convs, dual-layout store ===========
  for (int idx = blockIdx.x * 256 + tid; idx < NROWS * DPAD; idx += NBLK * 256) {
    int r = idx >> 6, t = idx & 63;
    if (t >= DW) {
      yf[idx] = 0;                               // K/Q pad cols must be zero
      if (t == 56) yfT[56 * NROWS + r] = 0x3F80; // ones row -> denominator
      continue;
    }
    int g = r / C3, c3 = r - g * C3;
    int flat = g * DW + t;
    int h = flat / HW, w = flat - h * HW;
    int grp = c3 / C_IN, c = c3 - grp * C_IN;
    const float* wk; int ks;
    if (grp == 0)      { wk = w3 + c * 9;  ks = 3; }
    else if (grp == 1) { wk = w5 + c * 25; ks = 5; }
    else               { wk = w7 + c * 49; ks = 7; }
    int p = ks >> 1;
    const float* xc = x + c * SSP;
    float val = 0.f;
    for (int dy = 0; dy < ks; dy++) {
      int hy = h + dy - p;
      if (hy < 0 || hy >= HW) continue;
      const float* xr = xc + hy * HW;
      const float* wr = wk + dy * ks;
      for (int dx = 0; dx < ks; dx++) {
        int wx = w + dx - p;
        if (wx < 0 || wx >= HW) continue;
        val += xr[wx] * wr[dx];
      }
    }
    ushort ov = f32_to_bf16_rne(val);
    yf[idx] = ov;
    yfT[t * NROWS + r] = ov;
  }

  grid_barrier(bar + 0);

  // ================= Phase 2: MFMA flash attention =========================
  {
    const int bid = blockIdx.x;
    const int qb = bid % 72, sp = bid / 72;
    const int w = tid >> 6, lane = tid & 63;
    const int q = lane >> 4, c = lane & 15;
    const int m0 = qb * 128 + w * 32;   // this wave's 32 queries
    ushort* Pm = (ushort*)(smem + 32768) + w * (32 * 72);

    // Q B-frags (pre-scaled by CSC): 16B loads straight from yf.
    bf16x8 qf[2][2];
#pragma unroll
    for (int mt = 0; mt < 2; mt++)
#pragma unroll
      for (int ds = 0; ds < 2; ds++) {
        bf16x8 raw = *(const bf16x8*)&yf[(m0 + mt * 16 + c) * 64 + ds * 32 + q * 8];
        short tmp[8];
#pragma unroll
        for (int j = 0; j < 8; j++)
          tmp[j] = (short)f32_to_bf16_rne(bf16_to_f32((ushort)raw[j]) * CSC);
        qf[mt][ds] = *(bf16x8*)tmp;
      }

    f32x4 o[4][2];
#pragma unroll
    for (int dt = 0; dt < 4; dt++)
#pragma unroll
      for (int mt = 0; mt < 2; mt++) o[dt][mt] = (f32x4)0.f;

    const int s0 = w, s1 = w + 4;   // this wave's DMA slab pair

    // ---- stage tile 0 into buffer 0 ----
    {
      const int k0 = (sp * TPS) * 64;
      char* Kb = smem;
      char* Vb = smem + 16384;
      async_copy16(yf + (k0 + lane) * 64 + s0 * 8, Kb + s0 * 1024);
      async_copy16(yf + (k0 + lane) * 64 + s1 * 8, Kb + s1 * 1024);
      async_copy16(yfT + lane * NROWS + k0 + s0 * 8, Vb + s0 * 1024);
      async_copy16(yfT + lane * NROWS + k0 + s1 * 8, Vb + s1 * 1024);
    }
    __syncthreads();

    for (int it = 0; it < TPS; it++) {
      const int cur = it & 1;
      if (it + 1 < TPS) {
        const int k1 = (sp * TPS + it + 1) * 64;
        char* Kb = smem + (cur ^ 1) * 8192;
        char* Vb = smem + 16384 + (cur ^ 1) * 8192;
        async_copy16(yf + (k1 + lane) * 64 + s0 * 8, Kb + s0 * 1024);
        async_copy16(yf + (k1 + lane) * 64 + s1 * 8, Kb + s1 * 1024);
        async_copy16(yfT + lane * NROWS + k1 + s0 * 8, Vb + s0 * 1024);
        async_copy16(yfT + lane * NROWS + k1 + s1 * 8, Vb + s1 * 1024);
      }

      const char* Kb = smem + cur * 8192;
      const char* Vb = smem + 16384 + cur * 8192;

      // ---- S^T = K . Q^T ----
      f32x4 s[4][2];
#pragma unroll
      for (int nt = 0; nt < 4; nt++) {
        bf16x8 a0 = *(const bf16x8*)(Kb + q * 1024 + (nt * 16 + c) * 16);
        bf16x8 a1 = *(const bf16x8*)(Kb + (4 + q) * 1024 + (nt * 16 + c) * 16);
        s[nt][0] = (f32x4)0.f; s[nt][1] = (f32x4)0.f;
        s[nt][0] = __builtin_amdgcn_mfma_f32_16x16x32_bf16(a0, qf[0][0], s[nt][0], 0, 0, 0);
        s[nt][1] = __builtin_amdgcn_mfma_f32_16x16x32_bf16(a0, qf[1][0], s[nt][1], 0, 0, 0);
        s[nt][0] = __builtin_amdgcn_mfma_f32_16x16x32_bf16(a1, qf[0][1], s[nt][0], 0, 0, 0);
        s[nt][1] = __builtin_amdgcn_mfma_f32_16x16x32_bf16(a1, qf[1][1], s[nt][1], 0, 0, 0);
      }

      // ---- p = exp2(s); pack bf16 P into wave-private LDS ----
#pragma unroll
      for (int nt = 0; nt < 4; nt++)
#pragma unroll
        for (int mt = 0; mt < 2; mt++) {
          f32x4 sv = s[nt][mt];
          float p0 = __builtin_amdgcn_exp2f(sv[0]);
          float p1 = __builtin_amdgcn_exp2f(sv[1]);
          float p2 = __builtin_amdgcn_exp2f(sv[2]);
          float p3 = __builtin_amdgcn_exp2f(sv[3]);
          uint d0 = (__float_as_uint(p0) >> 16) | (__float_as_uint(p1) & 0xffff0000u);
          uint d1 = (__float_as_uint(p2) >> 16) | (__float_as_uint(p3) & 0xffff0000u);
          *(uint2*)&Pm[(mt * 16 + c) * 72 + nt * 16 + q * 4] = make_uint2(d0, d1);
        }

      // ---- O^T += V^T . P^T ----
      bf16x8 bp[2][2];
#pragma unroll
      for (int mt = 0; mt < 2; mt++)
#pragma unroll
        for (int nc = 0; nc < 2; nc++)
          bp[mt][nc] = *(const bf16x8*)&Pm[(mt * 16 + c) * 72 + nc * 32 + q * 8];
#pragma unroll
      for (int dt = 0; dt < 4; dt++) {
        bf16x8 v0 = *(const bf16x8*)(Vb + q * 1024 + (dt * 16 + c) * 16);
        bf16x8 v1 = *(const bf16x8*)(Vb + (4 + q) * 1024 + (dt * 16 + c) * 16);
        o[dt][0] = __builtin_amdgcn_mfma_f32_16x16x32_bf16(v0, bp[0][0], o[dt][0], 0, 0, 0);
        o[dt][1] = __builtin_amdgcn_mfma_f32_16x16x32_bf16(v0, bp[1][0], o[dt][1], 0, 0, 0);
        o[dt][0] = __builtin_amdgcn_mfma_f32_16x16x32_bf16(v1, bp[0][1], o[dt][0], 0, 0, 0);
        o[dt][1] = __builtin_amdgcn_mfma_f32_16x16x32_bf16(v1, bp[1][1], o[dt][1], 0, 0, 0);
      }

      if (it + 1 < TPS) __syncthreads();
    }

    // ---- epilogue: each wave writes its own 32 queries' partials ----
#pragma unroll
    for (int dt = 0; dt < 4; dt++)
#pragma unroll
      for (int mt = 0; mt < 2; mt++)
#pragma unroll
        for (int r = 0; r < 4; r++) {
          int d = dt * 16 + q * 4 + r;
          int m = m0 + mt * 16 + c;
          float v = o[dt][mt][r];
          if (d < DW) {
            opart[(sp * DW + d) * NROWS + m] = f32_to_bf16_rne(v);
          } else if (d == 56) {
            esum_g[sp * NROWS + m] = v;   // softmax denominator (exact f32)
          }
        }
  }

  grid_barrier(bar + 64);   // second counter, 256 B away (separate line)

  // ================= Phase 3: merge + pointwise + bias + residual ==========
  if (blockIdx.x < 448) {
    float* vb = (float*)smem;                    // [7*145]
    float* inv_es = (float*)smem + 7 * 145;      // [144]
    const int g = blockIdx.x / 7, tch = blockIdx.x % 7;
    const int t0 = tch * 7;

    if (tid < 144) {
      int r = g * C3 + tid;
      float e = 0.f;
#pragma unroll
      for (int sp = 0; sp < NSPLIT; sp++) e += esum_g[sp * NROWS + r];
      inv_es[tid] = 1.f / e;
    }
    __syncthreads();

    for (int j = tid; j < 7 * 144; j += 256) {
      int tt = j / 144, i = j - tt * 144;
      int r = g * C3 + i, t = t0 + tt;
      float ov = 0.f;
#pragma unroll
      for (int sp = 0; sp < NSPLIT; sp++)
        ov += bf16_to_f32(opart[(sp * DW + t) * NROWS + r]);
      vb[tt * 145 + i] = ov * inv_es[i];
    }
    __syncthreads();

    for (int j = tid; j < C_IN * 7; j += 256) {
      int o = j / 7, tt = j - o * 7;
      int t = t0 + tt;
      const float* pwo = pwm + o * C3;
      const float* vrow = &vb[tt * 145];
      float a0 = 0.f, a1 = 0.f, a2 = 0.f, a3 = 0.f;
#pragma unroll
      for (int i = 0; i < C3; i += 4) {
        float4 wv = *(const float4*)&pwo[i];
        a0 += wv.x * vrow[i];
        a1 += wv.y * vrow[i + 1];
        a2 += wv.z * vrow[i + 2];
        a3 += wv.w * vrow[i + 3];
      }
      float acc = (a0 + a1) + (a2 + a3);
      int nh = g >> 3, nw = g & 7;
      int th = t / 7, tw = t - th * 7;
      int oidx = o * SSP + (nh * 7 + th) * HW + (nw * 7 + tw);
      out[oidx] = x[oidx] + pb[o] + acc;
    }
  }
}

// ---------------------------------------------------------------------------
extern "C" void kernel_launch(void* const* d_in, const int* in_sizes, int n_in,
                              void* d_out, int out_size, void* d_ws, size_t ws_size,
                              hipStream_t stream) {
  const float* x  = (const float*)d_in[0];
  const float* w3 = (const float*)d_in[1];
  const float* w5 = (const float*)d_in[2];
  const float* w7 = (const float*)d_in[3];
  const float* pw = (const float*)d_in[4];
  const float* pb = (const float*)d_in[5];
  float* out = (float*)d_out;
  char* ws = (char*)d_ws;

  ushort* yf    = (ushort*)(ws + YF_B);
  ushort* yfT   = (ushort*)(ws + YFT_B);
  ushort* opart = (ushort*)(ws + OPART_B);
  float*  esum  = (float*)(ws + ESUM_B);
  uint*   bar   = (uint*)(ws + BAR_B);

  // zero the barrier counters (d_ws is poisoned 0xAA before every launch)
  hipMemsetAsync(bar, 0, 512, stream);
  mega_kernel<<<NBLK, 256, 0, stream>>>(x, w3, w5, w7, pw, pb, yf, yfT, opart,
                                        esum, bar, out);
}

// Round 11
// 115.477 us; speedup vs baseline: 6.5281x; 2.2743x over previous
//
#include <hip/hip_runtime.h>

typedef unsigned int uint;
typedef unsigned short ushort;
typedef __attribute__((ext_vector_type(8))) short bf16x8;   // MFMA A/B frag (8 bf16)
typedef __attribute__((ext_vector_type(4))) float f32x4;    // MFMA C/D frag

// Problem constants
#define C_IN   48
#define C3     144
#define HW     56
#define SSP    3136
#define DW     49
#define DPAD   64            // padded head dim; yf cols 49..63 zero, yfT row 56 ones
#define NROWS  9216

// Attention config: block = 8 waves (512 thr) sharing LDS-staged K/V tiles,
// 256 queries per block. NSPLIT=12 -> 36x12 = 432 blocks, ALL co-resident
// (2 blocks/CU x 256 CU = 512 slots >= 432; no scheduling tail).
#define NSPLIT 12            // key splits
#define TPS    12            // tiles per split = 144/NSPLIT

#define CSC 0.02944245f      // 1/(49*ln2): exp2(qk*CSC)=exp(qk/49)

// ws layout (bytes):
//   yf    bf16 [9216][64]    : 0        .. 1179648
//   yfT   bf16 [64][9216]    : 1179648  .. 2359296
//   opart bf16 [12][49][9216]: 2359296  .. 13197312
//   esum  f32  [12][9216]    : 13197312 .. 13639680
#define YF_B    0
#define YFT_B   1179648
#define OPART_B 2359296
#define ESUM_B  (OPART_B + NSPLIT * DW * NROWS * 2)

__device__ __forceinline__ ushort f32_to_bf16_rne(float x) {
  uint b = __float_as_uint(x);
  b += 0x7fffu + ((b >> 16) & 1u);
  return (ushort)(b >> 16);
}
__device__ __forceinline__ float bf16_to_f32(ushort u) {
  return __uint_as_float(((uint)u) << 16);
}
__device__ __forceinline__ void async_copy16(const void* g, void* l) {
  __builtin_amdgcn_global_load_lds(
      (const __attribute__((address_space(1))) unsigned int*)g,
      (__attribute__((address_space(3))) unsigned int*)l, 16, 0, 0);
}

// ---------------------------------------------------------------------------
// Kernel 1: depthwise convs, thread per (r,t); 2304 blocks (9 waves/SIMD).
// Writes yf[r][64] coalesced AND yfT[t][r] as a per-lane scalar scatter.
// yf cols 49..63 = 0 (K/Q pad); yfT row 56 = 1.0 (softmax denom via PV MFMA).
// (byte-identical to R7's proven conv)
// ---------------------------------------------------------------------------
__global__ __launch_bounds__(256) void conv_kernel(
    const float* __restrict__ x, const float* __restrict__ w3,
    const float* __restrict__ w5, const float* __restrict__ w7,
    ushort* __restrict__ yf, ushort* __restrict__ yfT) {
  int idx = blockIdx.x * 256 + threadIdx.x;   // r*64 + t
  int r = idx >> 6, t = idx & 63;
  if (t >= DW) {
    yf[idx] = 0;                               // K/Q pad cols must be zero
    if (t == 56) yfT[56 * NROWS + r] = 0x3F80; // ones row -> denominator
    return;
  }
  int g = r / C3, c3 = r - g * C3;
  int flat = g * DW + t;
  int h = flat / HW, w = flat - h * HW;
  int grp = c3 / C_IN, c = c3 - grp * C_IN;
  const float* wk; int ks;
  if (grp == 0)      { wk = w3 + c * 9;  ks = 3; }
  else if (grp == 1) { wk = w5 + c * 25; ks = 5; }
  else               { wk = w7 + c * 49; ks = 7; }
  int p = ks >> 1;
  const float* xc = x + c * SSP;
  float val = 0.f;
  for (int dy = 0; dy < ks; dy++) {
    int hy = h + dy - p;
    if (hy < 0 || hy >= HW) continue;
    const float* xr = xc + hy * HW;
    const float* wr = wk + dy * ks;
    for (int dx = 0; dx < ks; dx++) {
      int wx = w + dx - p;
      if (wx < 0 || wx >= HW) continue;
      val += xr[wx] * wr[dx];
    }
  }
  ushort ov = f32_to_bf16_rne(val);
  yf[idx] = ov;
  yfT[t * NROWS + r] = ov;
}

// ---------------------------------------------------------------------------
// Kernel 2: MFMA flash attention, 8-wave blocks.
// Grid (36, 12): blockIdx.x = 256-query block, blockIdx.y = key split (12
// tiles of 64 keys). All 8 waves share one K/V double-buffer (staging traffic
// halves vs 4-wave blocks); each wave owns 32 queries end-to-end.
// LDS: [Kbuf0 8K][Kbuf1 8K][Vbuf0 8K][Vbuf1 8K][P 8x32x72 ushort 36,864B]
//    = 69632 B -> 2 blocks/CU = 16 waves/CU.
// K slab s (of 8): d-chunk s, addr s*1024 + key*16.
// V slab s (of 8): key-chunk s, addr s*1024 + d*16.
// yfT row 56 = ones => softmax denominator at d==56.
// ---------------------------------------------------------------------------
__global__ __launch_bounds__(512, 4) void attn_kernel(
    const ushort* __restrict__ yf, const ushort* __restrict__ yfT,
    ushort* __restrict__ opart, float* __restrict__ esum_g) {
  __shared__ __align__(16) char smem[69632];

  const int tid = threadIdx.x;
  const int w = tid >> 6, lane = tid & 63;
  const int q = lane >> 4, c = lane & 15;
  const int m0 = blockIdx.x * 256 + w * 32;   // this wave's 32 queries
  const int sp = blockIdx.y;
  ushort* Pm = (ushort*)(smem + 32768) + w * (32 * 72);

  // Q B-frags (pre-scaled by CSC): 16B loads straight from yf.
  bf16x8 qf[2][2];
#pragma unroll
  for (int mt = 0; mt < 2; mt++)
#pragma unroll
    for (int ds = 0; ds < 2; ds++) {
      bf16x8 raw = *(const bf16x8*)&yf[(m0 + mt * 16 + c) * 64 + ds * 32 + q * 8];
      short tmp[8];
#pragma unroll
      for (int j = 0; j < 8; j++)
        tmp[j] = (short)f32_to_bf16_rne(bf16_to_f32((ushort)raw[j]) * CSC);
      qf[mt][ds] = *(bf16x8*)tmp;
    }

  f32x4 o[4][2];
#pragma unroll
  for (int dt = 0; dt < 4; dt++)
#pragma unroll
    for (int mt = 0; mt < 2; mt++) o[dt][mt] = (f32x4)0.f;

  // this wave's DMA slabs: K slab w, V slab w (8 waves cover 8+8 slabs)
  // ---- stage tile 0 into buffer 0 ----
  {
    const int k0 = (sp * TPS) * 64;
    async_copy16(yf + (k0 + lane) * 64 + w * 8, smem + w * 1024);
    async_copy16(yfT + lane * NROWS + k0 + w * 8, smem + 16384 + w * 1024);
  }
  __syncthreads();

  for (int it = 0; it < TPS; it++) {
    const int cur = it & 1;
    // ---- fire DMA for next tile into the other buffer ----
    if (it + 1 < TPS) {
      const int k1 = (sp * TPS + it + 1) * 64;
      async_copy16(yf + (k1 + lane) * 64 + w * 8,
                   smem + (cur ^ 1) * 8192 + w * 1024);
      async_copy16(yfT + lane * NROWS + k1 + w * 8,
                   smem + 16384 + (cur ^ 1) * 8192 + w * 1024);
    }

    const char* Kb = smem + cur * 8192;
    const char* Vb = smem + 16384 + cur * 8192;

    // ---- S^T = K . Q^T (K frags from LDS) ----
    f32x4 s[4][2];
#pragma unroll
    for (int nt = 0; nt < 4; nt++) {
      bf16x8 a0 = *(const bf16x8*)(Kb + q * 1024 + (nt * 16 + c) * 16);
      bf16x8 a1 = *(const bf16x8*)(Kb + (4 + q) * 1024 + (nt * 16 + c) * 16);
      s[nt][0] = (f32x4)0.f; s[nt][1] = (f32x4)0.f;
      s[nt][0] = __builtin_amdgcn_mfma_f32_16x16x32_bf16(a0, qf[0][0], s[nt][0], 0, 0, 0);
      s[nt][1] = __builtin_amdgcn_mfma_f32_16x16x32_bf16(a0, qf[1][0], s[nt][1], 0, 0, 0);
      s[nt][0] = __builtin_amdgcn_mfma_f32_16x16x32_bf16(a1, qf[0][1], s[nt][0], 0, 0, 0);
      s[nt][1] = __builtin_amdgcn_mfma_f32_16x16x32_bf16(a1, qf[1][1], s[nt][1], 0, 0, 0);
    }

    // ---- p = exp2(s); pack bf16 P into wave-private LDS ----
#pragma unroll
    for (int nt = 0; nt < 4; nt++)
#pragma unroll
      for (int mt = 0; mt < 2; mt++) {
        f32x4 sv = s[nt][mt];
        float p0 = __builtin_amdgcn_exp2f(sv[0]);
        float p1 = __builtin_amdgcn_exp2f(sv[1]);
        float p2 = __builtin_amdgcn_exp2f(sv[2]);
        float p3 = __builtin_amdgcn_exp2f(sv[3]);
        uint d0 = (__float_as_uint(p0) >> 16) | (__float_as_uint(p1) & 0xffff0000u);
        uint d1 = (__float_as_uint(p2) >> 16) | (__float_as_uint(p3) & 0xffff0000u);
        *(uint2*)&Pm[(mt * 16 + c) * 72 + nt * 16 + q * 4] = make_uint2(d0, d1);
      }

    // ---- O^T += V^T . P^T (V frags from LDS) ----
    bf16x8 bp[2][2];
#pragma unroll
    for (int mt = 0; mt < 2; mt++)
#pragma unroll
      for (int nc = 0; nc < 2; nc++)
        bp[mt][nc] = *(const bf16x8*)&Pm[(mt * 16 + c) * 72 + nc * 32 + q * 8];
#pragma unroll
    for (int dt = 0; dt < 4; dt++) {
      bf16x8 v0 = *(const bf16x8*)(Vb + q * 1024 + (dt * 16 + c) * 16);
      bf16x8 v1 = *(const bf16x8*)(Vb + (4 + q) * 1024 + (dt * 16 + c) * 16);
      o[dt][0] = __builtin_amdgcn_mfma_f32_16x16x32_bf16(v0, bp[0][0], o[dt][0], 0, 0, 0);
      o[dt][1] = __builtin_amdgcn_mfma_f32_16x16x32_bf16(v0, bp[1][0], o[dt][1], 0, 0, 0);
      o[dt][0] = __builtin_amdgcn_mfma_f32_16x16x32_bf16(v1, bp[0][1], o[dt][0], 0, 0, 0);
      o[dt][1] = __builtin_amdgcn_mfma_f32_16x16x32_bf16(v1, bp[1][1], o[dt][1], 0, 0, 0);
    }

    // barrier: all waves done reading buf[cur]; drains next-tile DMA.
    if (it + 1 < TPS) __syncthreads();
  }

  // ---- epilogue: each wave writes its own 32 queries' partials ----
#pragma unroll
  for (int dt = 0; dt < 4; dt++)
#pragma unroll
    for (int mt = 0; mt < 2; mt++)
#pragma unroll
      for (int r = 0; r < 4; r++) {
        int d = dt * 16 + q * 4 + r;
        int m = m0 + mt * 16 + c;
        float v = o[dt][mt][r];
        if (d < DW) {
          opart[(sp * DW + d) * NROWS + m] = f32_to_bf16_rne(v);
        } else if (d == 56) {
          esum_g[sp * NROWS + m] = v;   // softmax denominator (exact f32)
        }
      }
}

// ---------------------------------------------------------------------------
// Kernel 3: fused merge + pointwise + bias + residual.
// Grid (64 windows, 7 t-chunks of 7). For window g all 144 channels are
// contiguous in opart rows: r = g*144 + i.  (R7-proven, NSPLIT=12)
// ---------------------------------------------------------------------------
__global__ __launch_bounds__(256) void fuse_pw_kernel(
    const ushort* __restrict__ opart, const float* __restrict__ esum_g,
    const float* __restrict__ x, const float* __restrict__ pw,
    const float* __restrict__ pb, float* __restrict__ out) {
  __shared__ float vb[7 * 145];
  __shared__ float inv_es[144];
  const int g = blockIdx.x, tch = blockIdx.y;
  const int t0 = tch * 7;
  const int tid = threadIdx.x;

  if (tid < 144) {
    int r = g * C3 + tid;
    float e = 0.f;
#pragma unroll
    for (int sp = 0; sp < NSPLIT; sp++) e += esum_g[sp * NROWS + r];
    inv_es[tid] = 1.f / e;
  }
  __syncthreads();

  for (int j = tid; j < 7 * 144; j += 256) {
    int tt = j / 144, i = j - tt * 144;
    int r = g * C3 + i, t = t0 + tt;
    float ov = 0.f;
#pragma unroll
    for (int sp = 0; sp < NSPLIT; sp++)
      ov += bf16_to_f32(opart[(sp * DW + t) * NROWS + r]);
    vb[tt * 145 + i] = ov * inv_es[i];
  }
  __syncthreads();

  for (int j = tid; j < C_IN * 7; j += 256) {
    int o = j / 7, tt = j - o * 7;
    int t = t0 + tt;
    const float* pwo = pw + o * C3;
    const float* vrow = &vb[tt * 145];
    float a0 = 0.f, a1 = 0.f, a2 = 0.f, a3 = 0.f;
#pragma unroll
    for (int i = 0; i < C3; i += 4) {
      float4 wv = *(const float4*)&pwo[i];
      a0 += wv.x * vrow[i];
      a1 += wv.y * vrow[i + 1];
      a2 += wv.z * vrow[i + 2];
      a3 += wv.w * vrow[i + 3];
    }
    float acc = (a0 + a1) + (a2 + a3);
    int nh = g >> 3, nw = g & 7;
    int th = t / 7, tw = t - th * 7;
    int oidx = o * SSP + (nh * 7 + th) * HW + (nw * 7 + tw);
    out[oidx] = x[oidx] + pb[o] + acc;
  }
}

// ---------------------------------------------------------------------------
extern "C" void kernel_launch(void* const* d_in, const int* in_sizes, int n_in,
                              void* d_out, int out_size, void* d_ws, size_t ws_size,
                              hipStream_t stream) {
  const float* x  = (const float*)d_in[0];
  const float* w3 = (const float*)d_in[1];
  const float* w5 = (const float*)d_in[2];
  const float* w7 = (const float*)d_in[3];
  const float* pw = (const float*)d_in[4];
  const float* pb = (const float*)d_in[5];
  float* out = (float*)d_out;
  char* ws = (char*)d_ws;

  ushort* yf    = (ushort*)(ws + YF_B);
  ushort* yfT   = (ushort*)(ws + YFT_B);
  ushort* opart = (ushort*)(ws + OPART_B);
  float*  esum  = (float*)(ws + ESUM_B);

  conv_kernel<<<(NROWS * DPAD) / 256, 256, 0, stream>>>(x, w3, w5, w7, yf, yfT);
  attn_kernel<<<dim3(NROWS / 256, NSPLIT), 512, 0, stream>>>(yf, yfT, opart, esum);
  fuse_pw_kernel<<<dim3(64, 7), 256, 0, stream>>>(opart, esum, x, pw, pb, out);
}